// Round 1
// baseline (40597.366 us; speedup 1.0000x reference)
//
#include <hip/hip_runtime.h>
#include <hip/hip_bf16.h>
#include <math.h>

#define B_  256
#define T_  1024
#define S_  8
#define H_  256
#define L_  32
#define RH_ 32
#define NC  16   // clusters
#define CB  16   // blocks per cluster
#define MB  16   // batch rows per cluster
#define NR  16   // H rows per block
#define WS  260  // padded LDS row stride in floats (16B-aligned, <=2-way bank conflict)
#define TPB 256

// ---- LDS float offsets ----
#define OFF_GH0   0
#define OFF_BB0H  (OFF_GH0  + NR*WS)
#define OFF_GX1   (OFF_BB0H + NR*WS)
#define OFF_GH1   (OFF_GX1  + NR*WS)
#define OFF_BB1X  (OFF_GH1  + NR*WS)
#define OFF_BB1H  (OFF_BB1X + NR*WS)
#define OFF_HA    (OFF_BB1H + NR*WS)
#define OFF_HB    (OFF_HA   + MB*WS)
#define OFF_GX0   (OFF_HB   + MB*WS)
#define OFF_BB0X  (OFF_GX0  + NR*S_)
#define OFF_BG0   (OFF_BB0X + NR*S_)
#define OFF_BF0   (OFF_BG0 + NR)
#define OFF_SP0   (OFF_BF0 + NR)
#define OFF_BG1   (OFF_SP0 + NR)
#define OFF_BF1   (OFF_BG1 + NR)
#define OFF_SP1   (OFF_BF1 + NR)
#define OFF_LNG   (OFF_SP1 + NR)
#define OFF_LNB   (OFF_LNG + S_)
#define OFF_XN    (OFF_LNB + S_)
#define OFF_DT    (OFF_XN  + MB*S_)
#define SMEM_FLOATS (OFF_DT + MB)
#define SMEM_BYTES  (SMEM_FLOATS * 4)

__device__ __forceinline__ void cluster_barrier(int* cnt, int target) {
    __syncthreads();                       // all threads' h-stores issued & drained (vmcnt 0 at barrier)
    if (threadIdx.x == 0) {
        __threadfence();                   // agent-scope release: push this XCD's L2 to coherence point
        __hip_atomic_fetch_add(cnt, 1, __ATOMIC_RELAXED, __HIP_MEMORY_SCOPE_AGENT);
        while (__hip_atomic_load(cnt, __ATOMIC_RELAXED, __HIP_MEMORY_SCOPE_AGENT) < target) {
            __builtin_amdgcn_s_sleep(2);
        }
        __threadfence();                   // agent-scope acquire: invalidate L1/L2 before re-reading h
    }
    __syncthreads();
}

__global__ void __launch_bounds__(TPB, 1)
liquid_cfc_kernel(const float* __restrict__ xs,      // [B,T,S]
                  const float* __restrict__ tstamp,  // [B,T]
                  const float* __restrict__ ln_g, const float* __restrict__ ln_b,
                  const float* __restrict__ bb_w0, const float* __restrict__ bb_b0,
                  const float* __restrict__ gx_w0, const float* __restrict__ gx_b0,
                  const float* __restrict__ gh_w0, const float* __restrict__ gb0,
                  const float* __restrict__ lt0,
                  const float* __restrict__ bb_w1, const float* __restrict__ bb_b1,
                  const float* __restrict__ gx_w1, const float* __restrict__ gx_b1,
                  const float* __restrict__ gh_w1, const float* __restrict__ gb1,
                  const float* __restrict__ lt1,
                  const float* __restrict__ lp_w, const float* __restrict__ lp_b,
                  const float* __restrict__ r1_w, const float* __restrict__ r1_b,
                  const float* __restrict__ r2_w, const float* __restrict__ r2_b,
                  float* __restrict__ out,
                  int* __restrict__ barriers,        // [NC*32]
                  float* __restrict__ h0g,           // [2,B,H] (zeroed)
                  float* __restrict__ h1g,           // [2,B,H] (zeroed)
                  float* __restrict__ latg)          // [B,L]
{
    extern __shared__ float sm[];
    const int tid = threadIdx.x;
    const int blk = blockIdx.x;
    const int c  = blk >> 4;      // cluster id (batch slice)
    const int j  = blk & 15;      // block-in-cluster (H-row slice)
    const int b0 = c * MB;
    const int r0 = j * NR;
    int* cnt = &barriers[c * 32];
    int nb = 0;                   // local barrier index

    // ---- one-time: load this block's weight slice into LDS ----
    for (int idx = tid; idx < NR * (H_/4); idx += TPB) {
        int r  = idx >> 6;        // 64 float4 per row
        int kk = idx & 63;
        reinterpret_cast<float4*>(&sm[OFF_GH0  + r*WS])[kk] = reinterpret_cast<const float4*>(&gh_w0[(r0+r)*H_])[kk];
        reinterpret_cast<float4*>(&sm[OFF_BB0H + r*WS])[kk] = reinterpret_cast<const float4*>(&bb_w0[(r0+r)*(S_+H_) + S_])[kk];
        reinterpret_cast<float4*>(&sm[OFF_GX1  + r*WS])[kk] = reinterpret_cast<const float4*>(&gx_w1[(r0+r)*H_])[kk];
        reinterpret_cast<float4*>(&sm[OFF_GH1  + r*WS])[kk] = reinterpret_cast<const float4*>(&gh_w1[(r0+r)*H_])[kk];
        reinterpret_cast<float4*>(&sm[OFF_BB1X + r*WS])[kk] = reinterpret_cast<const float4*>(&bb_w1[(r0+r)*(2*H_)])[kk];
        reinterpret_cast<float4*>(&sm[OFF_BB1H + r*WS])[kk] = reinterpret_cast<const float4*>(&bb_w1[(r0+r)*(2*H_) + H_])[kk];
    }
    if (tid < NR * S_) {
        int r = tid >> 3, s = tid & 7;
        sm[OFF_GX0  + tid] = gx_w0[(r0+r)*S_ + s];
        sm[OFF_BB0X + tid] = bb_w0[(r0+r)*(S_+H_) + s];
    }
    if (tid < NR) {
        sm[OFF_BG0 + tid] = gx_b0[r0+tid] + gb0[r0+tid];
        sm[OFF_BF0 + tid] = bb_b0[r0+tid];
        sm[OFF_SP0 + tid] = log1pf(expf(lt0[r0+tid]));
        sm[OFF_BG1 + tid] = gx_b1[r0+tid] + gb1[r0+tid];
        sm[OFF_BF1 + tid] = bb_b1[r0+tid];
        sm[OFF_SP1 + tid] = log1pf(expf(lt1[r0+tid]));
    }
    if (tid < S_) { sm[OFF_LNG + tid] = ln_g[tid]; sm[OFF_LNB + tid] = ln_b[tid]; }
    __syncthreads();

    const int r = tid & 15;
    const int b = tid >> 4;

    for (int t = 0; t < T_; ++t) {
        const int p = t & 1, q = 1 - p;

        // ---- stage h0_prev [MB,H] -> LDS hA ----
        for (int idx = tid; idx < MB * (H_/4); idx += TPB) {
            int bb = idx >> 6, kk = idx & 63;
            reinterpret_cast<float4*>(&sm[OFF_HA + bb*WS])[kk] =
                reinterpret_cast<const float4*>(&h0g[q*B_*H_ + (b0+bb)*H_])[kk];
        }
        // ---- layernorm x_t and dt for the 16 batch rows ----
        if (tid < MB) {
            const float* xp = &xs[((size_t)(b0+tid) * T_ + t) * S_];
            float v[S_]; float mu = 0.f;
            #pragma unroll
            for (int s = 0; s < S_; ++s) { v[s] = xp[s]; mu += v[s]; }
            mu *= (1.f / S_);
            float var = 0.f;
            #pragma unroll
            for (int s = 0; s < S_; ++s) { float d = v[s] - mu; var += d * d; }
            var *= (1.f / S_);
            float rstd = rsqrtf(var + 1e-5f);
            #pragma unroll
            for (int s = 0; s < S_; ++s)
                sm[OFF_XN + tid*S_ + s] = (v[s] - mu) * rstd * sm[OFF_LNG + s] + sm[OFF_LNB + s];
            const float* tp = &tstamp[(size_t)(b0+tid) * T_ + t];
            float dt = (t == 0) ? 1.0f : (tp[0] - tp[-1]);
            sm[OFF_DT + tid] = fmaxf(dt, 1e-6f);
        }
        __syncthreads();

        // ---- phase A: layer-0 cell, rows r0..r0+15 ----
        {
            float aG = sm[OFF_BG0 + r], aF = sm[OFF_BF0 + r];
            #pragma unroll
            for (int s = 0; s < S_; ++s) {
                float xv = sm[OFF_XN + b*S_ + s];
                aG += sm[OFF_GX0  + r*S_ + s] * xv;
                aF += sm[OFF_BB0X + r*S_ + s] * xv;
            }
            const float4* wg = reinterpret_cast<const float4*>(&sm[OFF_GH0  + r*WS]);
            const float4* wf = reinterpret_cast<const float4*>(&sm[OFF_BB0H + r*WS]);
            const float4* hv = reinterpret_cast<const float4*>(&sm[OFF_HA   + b*WS]);
            #pragma unroll 8
            for (int kk = 0; kk < H_/4; ++kk) {
                float4 h4 = hv[kk], g4 = wg[kk], f4 = wf[kk];
                aG += g4.x*h4.x + g4.y*h4.y + g4.z*h4.z + g4.w*h4.w;
                aF += f4.x*h4.x + f4.y*h4.y + f4.z*h4.z + f4.w*h4.w;
            }
            float g   = 1.f / (1.f + expf(-aG));
            float f   = tanhf(aF);
            float tau = sm[OFF_SP0 + r] + fabsf(g);
            float dec = expf(-sm[OFF_DT + b] * tau);
            float hp  = sm[OFF_HA + b*WS + (r0 + r)];
            h0g[p*B_*H_ + (b0+b)*H_ + (r0+r)] = dec * hp + (1.f - dec) * f;
        }
        cluster_barrier(cnt, (++nb) * CB);

        // ---- stage h0_cur -> hA, h1_prev -> hB ----
        for (int idx = tid; idx < MB * (H_/4); idx += TPB) {
            int bb = idx >> 6, kk = idx & 63;
            reinterpret_cast<float4*>(&sm[OFF_HA + bb*WS])[kk] =
                reinterpret_cast<const float4*>(&h0g[p*B_*H_ + (b0+bb)*H_])[kk];
            reinterpret_cast<float4*>(&sm[OFF_HB + bb*WS])[kk] =
                reinterpret_cast<const float4*>(&h1g[q*B_*H_ + (b0+bb)*H_])[kk];
        }
        __syncthreads();

        // ---- phase B: layer-1 cell ----
        {
            float aG = sm[OFF_BG1 + r], aF = sm[OFF_BF1 + r];
            const float4* wgx = reinterpret_cast<const float4*>(&sm[OFF_GX1  + r*WS]);
            const float4* wgh = reinterpret_cast<const float4*>(&sm[OFF_GH1  + r*WS]);
            const float4* wfx = reinterpret_cast<const float4*>(&sm[OFF_BB1X + r*WS]);
            const float4* wfh = reinterpret_cast<const float4*>(&sm[OFF_BB1H + r*WS]);
            const float4* h0v = reinterpret_cast<const float4*>(&sm[OFF_HA + b*WS]);
            const float4* h1v = reinterpret_cast<const float4*>(&sm[OFF_HB + b*WS]);
            #pragma unroll 4
            for (int kk = 0; kk < H_/4; ++kk) {
                float4 a4 = h0v[kk], b4 = h1v[kk];
                float4 w0 = wgx[kk], w1 = wgh[kk], w2 = wfx[kk], w3 = wfh[kk];
                aG += w0.x*a4.x + w0.y*a4.y + w0.z*a4.z + w0.w*a4.w;
                aG += w1.x*b4.x + w1.y*b4.y + w1.z*b4.z + w1.w*b4.w;
                aF += w2.x*a4.x + w2.y*a4.y + w2.z*a4.z + w2.w*a4.w;
                aF += w3.x*b4.x + w3.y*b4.y + w3.z*b4.z + w3.w*b4.w;
            }
            float g   = 1.f / (1.f + expf(-aG));
            float f   = tanhf(aF);
            float tau = sm[OFF_SP1 + r] + fabsf(g);
            float dec = expf(-sm[OFF_DT + b] * tau);
            float hp  = sm[OFF_HB + b*WS + (r0 + r)];
            h1g[p*B_*H_ + (b0+b)*H_ + (r0+r)] = dec * hp + (1.f - dec) * f;
        }
        cluster_barrier(cnt, (++nb) * CB);
    }

    // ---- head: latent = tanh(h1 @ lp_w.T + lp_b) ----
    // stage final h1 (parity 1) -> hB
    for (int idx = tid; idx < MB * (H_/4); idx += TPB) {
        int bb = idx >> 6, kk = idx & 63;
        reinterpret_cast<float4*>(&sm[OFF_HB + bb*WS])[kk] =
            reinterpret_cast<const float4*>(&h1g[1*B_*H_ + (b0+bb)*H_])[kk];
    }
    __syncthreads();
    if (tid < 2 * MB) {           // 32 threads: 16 batch x 2 latent rows per block
        int lb = tid >> 1;
        int l  = j * 2 + (tid & 1);
        const float4* wl = reinterpret_cast<const float4*>(&lp_w[l * H_]);
        const float4* hv = reinterpret_cast<const float4*>(&sm[OFF_HB + lb*WS]);
        float acc = lp_b[l];
        #pragma unroll 8
        for (int kk = 0; kk < H_/4; ++kk) {
            float4 w4 = wl[kk], h4 = hv[kk];
            acc += w4.x*h4.x + w4.y*h4.y + w4.z*h4.z + w4.w*h4.w;
        }
        float lat = tanhf(acc);
        out[(b0+lb)*L_ + l]  = lat;
        latg[(b0+lb)*L_ + l] = lat;
    }
    cluster_barrier(cnt, (++nb) * CB);

    // ---- risk head (block 0 of each cluster) ----
    if (j == 0 && tid < MB) {
        float latv[L_];
        #pragma unroll 8
        for (int l = 0; l < L_; ++l) latv[l] = latg[(b0+tid)*L_ + l];
        float acc2 = r2_b[0];
        #pragma unroll 2
        for (int j2 = 0; j2 < RH_; ++j2) {
            float z = r1_b[j2];
            #pragma unroll 8
            for (int l = 0; l < L_; ++l) z += r1_w[j2*L_ + l] * latv[l];
            float hid = 0.5f * z * (1.f + erff(z * 0.70710678118654752f)); // exact GELU
            acc2 += r2_w[j2] * hid;
        }
        out[B_*L_ + b0 + tid] = 1.f / (1.f + expf(-acc2));
    }
}

extern "C" void kernel_launch(void* const* d_in, const int* in_sizes, int n_in,
                              void* d_out, int out_size, void* d_ws, size_t ws_size,
                              hipStream_t stream) {
    (void)in_sizes; (void)n_in; (void)out_size; (void)ws_size;
    const float* xs     = (const float*)d_in[0];
    const float* tstamp = (const float*)d_in[1];
    const float* ln_g   = (const float*)d_in[2];
    const float* ln_b   = (const float*)d_in[3];
    const float* bb_w0  = (const float*)d_in[4];
    const float* bb_b0  = (const float*)d_in[5];
    const float* gx_w0  = (const float*)d_in[6];
    const float* gx_b0  = (const float*)d_in[7];
    const float* gh_w0  = (const float*)d_in[8];
    const float* gb0    = (const float*)d_in[9];
    const float* lt0    = (const float*)d_in[10];
    const float* bb_w1  = (const float*)d_in[11];
    const float* bb_b1  = (const float*)d_in[12];
    const float* gx_w1  = (const float*)d_in[13];
    const float* gx_b1  = (const float*)d_in[14];
    const float* gh_w1  = (const float*)d_in[15];
    const float* gb1    = (const float*)d_in[16];
    const float* lt1    = (const float*)d_in[17];
    const float* lp_w   = (const float*)d_in[18];
    const float* lp_b   = (const float*)d_in[19];
    const float* r1_w   = (const float*)d_in[20];
    const float* r1_b   = (const float*)d_in[21];
    const float* r2_w   = (const float*)d_in[22];
    const float* r2_b   = (const float*)d_in[23];

    // workspace carve: [0,4096) barriers, then h0[2,B,H], h1[2,B,H], lat[B,L]
    uint8_t* w = (uint8_t*)d_ws;
    int*   bar  = (int*)w;
    float* h0g  = (float*)(w + 4096);
    float* h1g  = h0g + 2 * B_ * H_;
    float* latg = h1g + 2 * B_ * H_;

    // zero barriers + h state (required: initial hidden state = 0, ws is poisoned 0xAA)
    hipMemsetAsync(d_ws, 0, 4096 + (size_t)4 * B_ * H_ * sizeof(float), stream);

    static bool attr_set = false;
    hipFuncSetAttribute((const void*)liquid_cfc_kernel,
                        hipFuncAttributeMaxDynamicSharedMemorySize, SMEM_BYTES);
    (void)attr_set;

    liquid_cfc_kernel<<<dim3(NC * CB), dim3(TPB), SMEM_BYTES, stream>>>(
        xs, tstamp, ln_g, ln_b,
        bb_w0, bb_b0, gx_w0, gx_b0, gh_w0, gb0, lt0,
        bb_w1, bb_b1, gx_w1, gx_b1, gh_w1, gb1, lt1,
        lp_w, lp_b, r1_w, r1_b, r2_w, r2_b,
        (float*)d_out, bar, h0g, h1g, latg);
}

// Round 2
// 5218.823 us; speedup vs baseline: 7.7790x; 7.7790x over previous
//
#include <hip/hip_runtime.h>
#include <hip/hip_bf16.h>
#include <math.h>

#define B_  256
#define T_  1024
#define S_  8
#define H_  256
#define L_  32
#define RH_ 32
#define NC  16   // clusters (batch groups of 16)
#define CB  16   // blocks per cluster (16 H-rows each)
#define MB  16   // batch rows per cluster
#define NR  16   // H rows per block
#define TPB 256  // 4 waves: w0=layer0 MFMA, w1=layer1 x-side MFMA, w2=layer1 h-side MFMA, w3=LN/dt
#define FH  (B_*H_)   // 65536 floats per parity plane

typedef __attribute__((ext_vector_type(8))) short bf16x8;   // 8 bf16 = 4 VGPRs
typedef __attribute__((ext_vector_type(4))) float f32x4;
typedef unsigned long long ull;

__device__ __forceinline__ void split_bf16(float v, short& hi, short& lo) {
    unsigned ub = __float_as_uint(v);
    float hf = __uint_as_float(ub & 0xffff0000u);   // truncate to bf16 (exact residual below)
    hi = (short)(ub >> 16);
    lo = (short)(__float_as_uint(v - hf) >> 16);    // residual truncated to bf16: ~2^-16 rel total
}

__global__ void __launch_bounds__(TPB, 1)
liquid_cfc_mfma(const float* __restrict__ xs,      // [B,T,S]
                const float* __restrict__ tstamp,  // [B,T]
                const float* __restrict__ ln_g, const float* __restrict__ ln_b,
                const float* __restrict__ bb_w0, const float* __restrict__ bb_b0,
                const float* __restrict__ gx_w0, const float* __restrict__ gx_b0,
                const float* __restrict__ gh_w0, const float* __restrict__ gb0,
                const float* __restrict__ lt0,
                const float* __restrict__ bb_w1, const float* __restrict__ bb_b1,
                const float* __restrict__ gx_w1, const float* __restrict__ gx_b1,
                const float* __restrict__ gh_w1, const float* __restrict__ gb1,
                const float* __restrict__ lt1,
                const float* __restrict__ lp_w, const float* __restrict__ lp_b,
                const float* __restrict__ r1_w, const float* __restrict__ r1_b,
                const float* __restrict__ r2_w, const float* __restrict__ r2_b,
                float* __restrict__ out,
                int*   bar,     // [NC*64] cluster flags, 256B apart
                float* h0pub,   // [2][B][H] fp32, device-coherent exchange
                float* h1pub,   // [2][B][H]
                float* latg)    // [B][L]
{
    const int tid  = threadIdx.x, lane = tid & 63, wid = tid >> 6;
    const int blk  = blockIdx.x,  c = blk >> 4,    j  = blk & 15;
    const int b0   = c * MB,      r0 = j * NR;
    const int n    = lane & 15,   quad = lane >> 4;
    int* cnt = &bar[c * 64];

    __shared__ float s_xn[16][8];            // layernormed x_t (this epoch)
    __shared__ float s_dt[2][16];            // dt double-buffered by epoch parity
    __shared__ float s_gx0[16][8], s_bb0x[16][8];
    __shared__ float s_bg0[16], s_bf0[16], s_sp0[16];
    __shared__ float s_bg1[16], s_bf1[16], s_sp1[16];
    __shared__ float s_pg[16][16], s_pf[16][16];   // wave1 -> wave2 partials

    // ---- one-time LDS init ----
    if (tid < 16) {
        s_bg0[tid] = gx_b0[r0+tid] + gb0[r0+tid];
        s_bf0[tid] = bb_b0[r0+tid];
        s_sp0[tid] = log1pf(expf(lt0[r0+tid]));
        s_bg1[tid] = gx_b1[r0+tid] + gb1[r0+tid];
        s_bf1[tid] = bb_b1[r0+tid];
        s_sp1[tid] = log1pf(expf(lt1[r0+tid]));
    }
    if (tid < 128) {
        int r = tid >> 3, s = tid & 7;
        s_gx0[r][s]  = gx_w0[(r0+r)*S_ + s];
        s_bb0x[r][s] = bb_w0[(r0+r)*(S_+H_) + s];
    }

    // ---- one-time: weight slices -> bf16 hi/lo MFMA B-fragments in registers ----
    // wave0: gh_w0 (g), bb_w0 h-part (f)   [A = h0]
    // wave1: gx_w1 (g), bb_w1 x-part (f)   [A = h0]
    // wave2: gh_w1 (g), bb_w1 h-part (f)   [A = h1]
    bf16x8 whi[2][8], wlo[2][8];
    if (wid < 3) {
        const float* base[2]; int st[2], of[2];
        if (wid == 0) { base[0]=gh_w0; st[0]=H_;   of[0]=0;  base[1]=bb_w0; st[1]=S_+H_; of[1]=S_; }
        else if (wid == 1) { base[0]=gx_w1; st[0]=H_; of[0]=0; base[1]=bb_w1; st[1]=2*H_; of[1]=0; }
        else { base[0]=gh_w1; st[0]=H_; of[0]=0; base[1]=bb_w1; st[1]=2*H_; of[1]=H_; }
        int row = r0 + n;
        for (int mt = 0; mt < 2; ++mt) {
            const float* bp = base[mt] + (size_t)row * st[mt] + of[mt];
            for (int kb = 0; kb < 8; ++kb) {
                const float* sp = bp + kb*32 + quad*8;
                #pragma unroll
                for (int jj = 0; jj < 8; ++jj) {
                    short h_, l_;
                    split_bf16(sp[jj], h_, l_);
                    whi[mt][kb][jj] = h_; wlo[mt][kb][jj] = l_;
                }
            }
        }
    }
    float lngv[8], lnbv[8];
    if (wid == 3 && lane < 16) {
        #pragma unroll
        for (int s = 0; s < 8; ++s) { lngv[s] = ln_g[s]; lnbv[s] = ln_b[s]; }
    }
    float h0own[4] = {0.f,0.f,0.f,0.f};   // wave0: own slice of h0 (fp32 exact recurrent state)
    float h1own[4] = {0.f,0.f,0.f,0.f};   // wave2: own slice of h1
    float tsPrev = 0.f;
    __syncthreads();

    // ---- main loop: epoch t computes layer0(step t) and layer1(step t-1) ----
    for (int t = 0; t <= T_; ++t) {
        const int p = t & 1, q = 1 - p;
        const bool act = (wid == 0 || wid == 3) ? (t < T_) : (t >= 1);

        // wave3: layernorm x_t + dt
        if (wid == 3 && act && lane < 16) {
            int m = lane;
            const float* xp = xs + ((size_t)(b0+m) * T_ + t) * S_;
            float v[8]; float mu = 0.f;
            #pragma unroll
            for (int s = 0; s < 8; ++s) { v[s] = xp[s]; mu += v[s]; }
            mu *= 0.125f;
            float var = 0.f;
            #pragma unroll
            for (int s = 0; s < 8; ++s) { float d = v[s] - mu; var += d * d; }
            var *= 0.125f;
            float rstd = rsqrtf(var + 1e-5f);
            #pragma unroll
            for (int s = 0; s < 8; ++s) s_xn[m][s] = (v[s] - mu) * rstd * lngv[s] + lnbv[s];
            float ts = tstamp[(size_t)(b0+m) * T_ + t];
            float dt = (t == 0) ? 1.0f : fmaxf(ts - tsPrev, 1e-6f);
            tsPrev = ts;
            s_dt[p][m] = dt;
        }

        // waves 0-2: coherent A load (fp32), bf16 hi/lo split, 3-term MFMA
        f32x4 accg = {0.f,0.f,0.f,0.f}, accf = {0.f,0.f,0.f,0.f};
        if (wid < 3 && act) {
            float* apub = (wid == 2) ? h1pub : h0pub;
            ull* asrc = (ull*)(apub + (size_t)q * FH + (size_t)(b0+n) * H_);
            ull araw[32];
            #pragma unroll
            for (int u = 0; u < 32; ++u) {
                int kb = u >> 2, uu = u & 3;
                araw[u] = __hip_atomic_load(&asrc[kb*16 + quad*4 + uu],
                                            __ATOMIC_RELAXED, __HIP_MEMORY_SCOPE_AGENT);
            }
            bf16x8 ahi[8], alo[8];
            #pragma unroll
            for (int kb = 0; kb < 8; ++kb) {
                #pragma unroll
                for (int uu = 0; uu < 4; ++uu) {
                    ull d = araw[kb*4 + uu];
                    float f0 = __uint_as_float((unsigned)d);
                    float f1 = __uint_as_float((unsigned)(d >> 32));
                    short h_, l_;
                    split_bf16(f0, h_, l_); ahi[kb][uu*2]   = h_; alo[kb][uu*2]   = l_;
                    split_bf16(f1, h_, l_); ahi[kb][uu*2+1] = h_; alo[kb][uu*2+1] = l_;
                }
            }
            #pragma unroll
            for (int kb = 0; kb < 8; ++kb) {
                accg = __builtin_amdgcn_mfma_f32_16x16x32_bf16(ahi[kb], whi[0][kb], accg, 0,0,0);
                accg = __builtin_amdgcn_mfma_f32_16x16x32_bf16(alo[kb], whi[0][kb], accg, 0,0,0);
                accg = __builtin_amdgcn_mfma_f32_16x16x32_bf16(ahi[kb], wlo[0][kb], accg, 0,0,0);
                accf = __builtin_amdgcn_mfma_f32_16x16x32_bf16(ahi[kb], whi[1][kb], accf, 0,0,0);
                accf = __builtin_amdgcn_mfma_f32_16x16x32_bf16(alo[kb], whi[1][kb], accf, 0,0,0);
                accf = __builtin_amdgcn_mfma_f32_16x16x32_bf16(ahi[kb], wlo[1][kb], accf, 0,0,0);
            }
            if (wid == 1) {
                #pragma unroll
                for (int i = 0; i < 4; ++i) {
                    s_pg[quad*4+i][n] = accg[i];
                    s_pf[quad*4+i][n] = accf[i];
                }
            }
        }
        __syncthreads();   // xn/dt ready; wave1 partials ready

        // wave0 epilogue: layer-0 cell for step t, publish h0[t]
        if (wid == 0 && act) {
            #pragma unroll
            for (int i = 0; i < 4; ++i) {
                int m = quad*4 + i;
                float aG = accg[i] + s_bg0[n];
                float aF = accf[i] + s_bf0[n];
                #pragma unroll
                for (int s = 0; s < 8; ++s) {
                    float xv = s_xn[m][s];
                    aG += s_gx0[n][s] * xv;
                    aF += s_bb0x[n][s] * xv;
                }
                float g   = 1.f / (1.f + expf(-aG));
                float f   = tanhf(aF);
                float dec = expf(-s_dt[p][m] * (s_sp0[n] + fabsf(g)));
                h0own[i]  = dec * h0own[i] + (1.f - dec) * f;
                __hip_atomic_store(&h0pub[(size_t)p*FH + (size_t)(b0+m)*H_ + (r0+n)],
                                   h0own[i], __ATOMIC_RELAXED, __HIP_MEMORY_SCOPE_AGENT);
            }
        }
        // wave2 epilogue: layer-1 cell for step t-1, publish h1[t-1]
        if (wid == 2 && t >= 1) {
            #pragma unroll
            for (int i = 0; i < 4; ++i) {
                int m = quad*4 + i;
                float aG = accg[i] + s_pg[m][n] + s_bg1[n];
                float aF = accf[i] + s_pf[m][n] + s_bf1[n];
                float g   = 1.f / (1.f + expf(-aG));
                float f   = tanhf(aF);
                float dec = expf(-s_dt[q][m] * (s_sp1[n] + fabsf(g)));
                h1own[i]  = dec * h1own[i] + (1.f - dec) * f;
                __hip_atomic_store(&h1pub[(size_t)p*FH + (size_t)(b0+m)*H_ + (r0+n)],
                                   h1own[i], __ATOMIC_RELAXED, __HIP_MEMORY_SCOPE_AGENT);
            }
        }

        // cluster barrier: syncthreads drains all waves' stores (vmcnt(0) before s_barrier);
        // device-scope write-through stores are then globally visible -> no cache flush needed.
        __syncthreads();
        if (tid == 0) {
            __hip_atomic_fetch_add(cnt, 1, __ATOMIC_RELAXED, __HIP_MEMORY_SCOPE_AGENT);
            int tgt = (t + 1) * CB;
            while (__hip_atomic_load(cnt, __ATOMIC_RELAXED, __HIP_MEMORY_SCOPE_AGENT) < tgt) { }
        }
        __syncthreads();
    }

    // ---- latent head: h1 final = step T-1, published at epoch T (parity 0) ----
    if (tid < 32) {
        int lb = tid >> 1;
        int l  = j*2 + (tid & 1);
        float* hsrc = h1pub + (size_t)(b0+lb) * H_;   // parity 0 plane
        float acc = lp_b[l];
        #pragma unroll 8
        for (int k = 0; k < H_; ++k)
            acc += __hip_atomic_load(&hsrc[k], __ATOMIC_RELAXED, __HIP_MEMORY_SCOPE_AGENT)
                   * lp_w[l*H_ + k];
        float lat = tanhf(acc);
        out[(b0+lb)*L_ + l] = lat;
        __hip_atomic_store(&latg[(b0+lb)*L_ + l], lat,
                           __ATOMIC_RELAXED, __HIP_MEMORY_SCOPE_AGENT);
    }
    __syncthreads();
    if (tid == 0) {
        __hip_atomic_fetch_add(cnt, 1, __ATOMIC_RELAXED, __HIP_MEMORY_SCOPE_AGENT);
        int tgt = (T_ + 2) * CB;
        while (__hip_atomic_load(cnt, __ATOMIC_RELAXED, __HIP_MEMORY_SCOPE_AGENT) < tgt) { }
    }
    __syncthreads();

    // ---- risk head (block 0 of each cluster) ----
    if (j == 0 && tid < 16) {
        float latv[L_];
        #pragma unroll
        for (int l = 0; l < L_; ++l)
            latv[l] = __hip_atomic_load(&latg[(b0+tid)*L_ + l],
                                        __ATOMIC_RELAXED, __HIP_MEMORY_SCOPE_AGENT);
        float acc2 = r2_b[0];
        for (int j2 = 0; j2 < RH_; ++j2) {
            float z = r1_b[j2];
            #pragma unroll
            for (int l = 0; l < L_; ++l) z += r1_w[j2*L_ + l] * latv[l];
            float hid = 0.5f * z * (1.f + erff(z * 0.70710678118654752f)); // exact GELU
            acc2 += r2_w[j2] * hid;
        }
        out[B_*L_ + b0 + tid] = 1.f / (1.f + expf(-acc2));
    }
}

extern "C" void kernel_launch(void* const* d_in, const int* in_sizes, int n_in,
                              void* d_out, int out_size, void* d_ws, size_t ws_size,
                              hipStream_t stream) {
    (void)in_sizes; (void)n_in; (void)out_size; (void)ws_size;
    const float* xs     = (const float*)d_in[0];
    const float* tstamp = (const float*)d_in[1];
    const float* ln_g   = (const float*)d_in[2];
    const float* ln_b   = (const float*)d_in[3];
    const float* bb_w0  = (const float*)d_in[4];
    const float* bb_b0  = (const float*)d_in[5];
    const float* gx_w0  = (const float*)d_in[6];
    const float* gx_b0  = (const float*)d_in[7];
    const float* gh_w0  = (const float*)d_in[8];
    const float* gb0    = (const float*)d_in[9];
    const float* lt0    = (const float*)d_in[10];
    const float* bb_w1  = (const float*)d_in[11];
    const float* bb_b1  = (const float*)d_in[12];
    const float* gx_w1  = (const float*)d_in[13];
    const float* gx_b1  = (const float*)d_in[14];
    const float* gh_w1  = (const float*)d_in[15];
    const float* gb1    = (const float*)d_in[16];
    const float* lt1    = (const float*)d_in[17];
    const float* lp_w   = (const float*)d_in[18];
    const float* lp_b   = (const float*)d_in[19];
    const float* r1_w   = (const float*)d_in[20];
    const float* r1_b   = (const float*)d_in[21];
    const float* r2_w   = (const float*)d_in[22];
    const float* r2_b   = (const float*)d_in[23];

    // ws carve: bar 4KB | h0pub 2*FH | h1pub 2*FH | latg B*L
    uint8_t* w = (uint8_t*)d_ws;
    int*   bar   = (int*)w;
    float* h0pub = (float*)(w + 4096);
    float* h1pub = h0pub + 2 * FH;
    float* latg  = h1pub + 2 * FH;

    // zero flags + both parities of h state (epoch 0/1 read zeros; ws poisoned 0xAA)
    hipMemsetAsync(d_ws, 0, 4096 + (size_t)(4 * FH + B_ * L_) * sizeof(float), stream);

    liquid_cfc_mfma<<<dim3(NC * CB), dim3(TPB), 0, stream>>>(
        xs, tstamp, ln_g, ln_b,
        bb_w0, bb_b0, gx_w0, gx_b0, gh_w0, gb0, lt0,
        bb_w1, bb_b1, gx_w1, gx_b1, gh_w1, gb1, lt1,
        lp_w, lp_b, r1_w, r1_b, r2_w, r2_b,
        (float*)d_out, bar, h0pub, h1pub, latg);
}